// Round 3
// baseline (145.921 us; speedup 1.0000x reference)
//
#include <hip/hip_runtime.h>
#include <math.h>

#define NBLK_B 8  // phase-B persistent blocks (cols of W1 partitioned 8 x 128)

__device__ __forceinline__ float rho(float s) {
  return fminf(fmaxf(s, 0.0f), 1.0f);
}

// d/ds clip(s,0,1) with JAX maximum/minimum tie-gradient = 0.5
__device__ __forceinline__ float drho(float s) {
  if (s < 0.0f || s > 1.0f) return 0.0f;
  float g = 1.0f;
  if (s == 0.0f) g *= 0.5f;
  if (s == 1.0f) g *= 0.5f;
  return g;
}

// ---------------- Phase A: per-block partials of c0 = rho(x) @ W0 ----------
template <int ROWS>
__global__ __launch_bounds__(256) void k1_xw0(const float* __restrict__ x,
                                              const float* __restrict__ W0,
                                              float* __restrict__ part,
                                              int* __restrict__ flags) {
  __shared__ float xs[ROWS];
  __shared__ float red[8][132];
  const int t = threadIdx.x;
  const int b = blockIdx.x;
  if (b == 0 && t < NBLK_B) flags[t * 32] = 0;  // reset phase-B flags
  const int r0 = b * ROWS;
  for (int i = t; i < ROWS; i += 256) xs[i] = rho(x[r0 + i]);
  __syncthreads();
  const int cq = t & 31;   // float4 column group (32 x 4 = 128 cols)
  const int rg = t >> 5;   // row group 0..7
  constexpr int GR = ROWS / 8;
  const float4* __restrict__ W4 = reinterpret_cast<const float4*>(W0);
  float ax = 0.f, ay = 0.f, az = 0.f, aw = 0.f;
  const int base = (r0 + rg * GR) * 32 + cq;
#pragma unroll 8
  for (int i = 0; i < GR; ++i) {
    const float xv = xs[rg * GR + i];
    const float4 w = W4[base + i * 32];
    ax = fmaf(xv, w.x, ax);
    ay = fmaf(xv, w.y, ay);
    az = fmaf(xv, w.z, az);
    aw = fmaf(xv, w.w, aw);
  }
  red[rg][cq * 4 + 0] = ax;
  red[rg][cq * 4 + 1] = ay;
  red[rg][cq * 4 + 2] = az;
  red[rg][cq * 4 + 3] = aw;
  __syncthreads();
  if (t < 128) {
    float s = 0.f;
#pragma unroll
    for (int g = 0; g < 8; ++g) s += red[g][t];
    part[b * 128 + t] = s;
  }
}

// ---------------- Phase B: persistent 8-block Adam iterator -----------------
// Schedule per iter: accB(local) -> o-update -> PUBLISH a-partial(t+1)
// -> poll a(t) (already ~1 iter old -> hits immediately) -> h-update.
// a-partials ride a 4-deep slot ring (slot = iter & 3).
__global__ __launch_bounds__(256) void k2_iter(const float* __restrict__ part,
                                               const int npart,
                                               const float* __restrict__ W1,
                                               const float* __restrict__ b1,
                                               const float* __restrict__ b2,
                                               const int* __restrict__ niterp,
                                               float* __restrict__ aPartG,
                                               int* __restrict__ flags,
                                               float* __restrict__ out) {
  __shared__ float w1s[128 * 128];  // 64 KB, elem (j,c) at j*128 + (c ^ (j&31))
  __shared__ float rhs_[128];
  __shared__ float ros_[128];
  __shared__ float c0s[128];
  __shared__ float b1s[128];
  __shared__ float bpart[2][128];
  __shared__ float apl[2][128];
  __shared__ float red[8][132];

  const int t = threadIdx.x;
  const int p = blockIdx.x;
  const int jk = t & 127;
  const int half = t >> 7;

  // stage W1[:, 128p:128p+128)  (row stride 1024 floats = 256 float4)
  const float4* __restrict__ W14 = reinterpret_cast<const float4*>(W1);
#pragma unroll
  for (int itr = 0; itr < 16; ++itr) {
    const int e4 = itr * 256 + t;
    const int j = e4 >> 5;
    const int c4 = e4 & 31;
    const float4 w = W14[j * 256 + p * 32 + c4];
    const int rb = j * 128;
    const int sw = j & 31;
    const int c = c4 * 4;
    w1s[rb + ((c + 0) ^ sw)] = w.x;
    w1s[rb + ((c + 1) ^ sw)] = w.y;
    w1s[rb + ((c + 2) ^ sw)] = w.z;
    w1s[rb + ((c + 3) ^ sw)] = w.w;
  }
  // c0 = column-sum of ALL of part[npart][128], identical fixed order in every
  // block (bit-identical c0 -> h stays replicated exactly). No exchange.
  {
    const int cq = t & 31;
    const int rg = t >> 5;
    const float4* __restrict__ p4 = reinterpret_cast<const float4*>(part);
    float ax = 0.f, ay = 0.f, az = 0.f, aw = 0.f;
    for (int r = rg; r < npart; r += 8) {
      const float4 v = p4[r * 32 + cq];
      ax += v.x; ay += v.y; az += v.z; aw += v.w;
    }
    red[rg][cq * 4 + 0] = ax;
    red[rg][cq * 4 + 1] = ay;
    red[rg][cq * 4 + 2] = az;
    red[rg][cq * 4 + 3] = aw;
  }
  const int niter = *niterp;
  const float b2v = (half == 0) ? b2[p * 128 + jk] : 0.f;
  __syncthreads();
  if (half == 0) {
    float s = 0.f;
#pragma unroll
    for (int g = 0; g < 8; ++g) s += red[g][jk];
    c0s[jk] = s;
    b1s[jk] = b1[jk];
    rhs_[jk] = 0.f;
    ros_[jk] = 0.f;
    // pre-publish a(1) = W1 @ rho(o_1=0) = 0 into slot 1
    __hip_atomic_store(&aPartG[1 * 1024 + p * 128 + jk], 0.f,
                       __ATOMIC_RELAXED, __HIP_MEMORY_SCOPE_AGENT);
  }
  __syncthreads();
  if (t == 0) {
    __threadfence();
    __hip_atomic_store(&flags[p * 32], 1, __ATOMIC_RELEASE,
                       __HIP_MEMORY_SCOPE_AGENT);
  }

  float hreg = 0.f, mh = 0.f, vh = 0.f;
  float oreg = 0.f, mo = 0.f, vo = 0.f;
  const int x0 = half * 64;

  for (int it = 1; it <= niter; ++it) {
    const float tf = (float)it;
    const float bc1 = 1.0f - powf(0.9f, tf);
    const float bc2 = 1.0f - powf(0.999f, tf);
    // 1) accB = rho(h_t) @ W1[:,own] over own 64 rows (4-way split accum)
    {
      float a0 = 0.f, a1 = 0.f, a2 = 0.f, a3 = 0.f;
#pragma unroll 4
      for (int u = 0; u < 64; u += 4) {
        const int j0 = x0 + u;
        a0 = fmaf(rhs_[j0 + 0], w1s[(j0 + 0) * 128 + (jk ^ ((j0 + 0) & 31))], a0);
        a1 = fmaf(rhs_[j0 + 1], w1s[(j0 + 1) * 128 + (jk ^ ((j0 + 1) & 31))], a1);
        a2 = fmaf(rhs_[j0 + 2], w1s[(j0 + 2) * 128 + (jk ^ ((j0 + 2) & 31))], a2);
        a3 = fmaf(rhs_[j0 + 3], w1s[(j0 + 3) * 128 + (jk ^ ((j0 + 3) & 31))], a3);
      }
      bpart[half][jk] = (a0 + a1) + (a2 + a3);
    }
    __syncthreads();  // A
    // 2) o-update (purely local) -> o_{t+1}; publish rho(o_{t+1})
    if (half == 0) {
      const float bsum = bpart[0][jk] + bpart[1][jk];
      const float rot = rho(oreg);
      const float go = drho(oreg) * (rot - b2v - bsum);
      mo = 0.9f * mo + 0.1f * go;
      vo = 0.999f * vo + 0.001f * (go * go);
      oreg = oreg - 0.01f * (mo / bc1) / (sqrtf(vo / bc2) + 1e-8f);
      ros_[jk] = rho(oreg);
    }
    __syncthreads();  // B
    // 3) accA(t+1) = W1[own cols] @ rho(o_{t+1}) -> publish EARLY (1 iter ahead)
    {
      float a0 = 0.f, a1 = 0.f, a2 = 0.f, a3 = 0.f;
#pragma unroll 4
      for (int u = 0; u < 64; u += 4) {
        const int c0i = x0 + u;
        a0 = fmaf(w1s[jk * 128 + ((c0i + 0) ^ (jk & 31))], ros_[c0i + 0], a0);
        a1 = fmaf(w1s[jk * 128 + ((c0i + 1) ^ (jk & 31))], ros_[c0i + 1], a1);
        a2 = fmaf(w1s[jk * 128 + ((c0i + 2) ^ (jk & 31))], ros_[c0i + 2], a2);
        a3 = fmaf(w1s[jk * 128 + ((c0i + 3) ^ (jk & 31))], ros_[c0i + 3], a3);
      }
      apl[half][jk] = (a0 + a1) + (a2 + a3);
    }
    __syncthreads();  // C
    const int wslot = (it + 1) & 3;
    if (half == 0)
      __hip_atomic_store(&aPartG[wslot * 1024 + p * 128 + jk],
                         apl[0][jk] + apl[1][jk], __ATOMIC_RELAXED,
                         __HIP_MEMORY_SCOPE_AGENT);
    __syncthreads();  // D
    if (t == 0) {
      __threadfence();
      __hip_atomic_store(&flags[p * 32], it + 1, __ATOMIC_RELEASE,
                         __HIP_MEMORY_SCOPE_AGENT);
    }
    // 4) poll for a(t) — published a full iteration ago, should hit first try
    if (t < NBLK_B) {
      while (__hip_atomic_load(&flags[t * 32], __ATOMIC_ACQUIRE,
                               __HIP_MEMORY_SCOPE_AGENT) < it)
        __builtin_amdgcn_s_sleep(1);
    }
    __syncthreads();  // E
    // 5) h-update (replicated, bit-identical in every block)
    if (half == 0) {
      const int rslot = it & 3;
      float a = 0.f;
#pragma unroll
      for (int q = 0; q < NBLK_B; ++q)
        a += __hip_atomic_load(&aPartG[rslot * 1024 + q * 128 + jk],
                               __ATOMIC_RELAXED, __HIP_MEMORY_SCOPE_AGENT);
      const float gh = drho(hreg) * (rhs_[jk] - b1s[jk] - c0s[jk] - a);
      mh = 0.9f * mh + 0.1f * gh;
      vh = 0.999f * vh + 0.001f * (gh * gh);
      hreg = hreg - 0.01f * (mh / bc1) / (sqrtf(vh / bc2) + 1e-8f);
      rhs_[jk] = rho(hreg);
    }
    __syncthreads();  // F
  }
  if (half == 0) out[p * 128 + jk] = oreg;
}

extern "C" void kernel_launch(void* const* d_in, const int* in_sizes, int n_in,
                              void* d_out, int out_size, void* d_ws,
                              size_t ws_size, hipStream_t stream) {
  const float* x  = (const float*)d_in[0];
  // d_in[1] = b0: constant in E w.r.t. (h,o) -> never needed
  const float* b1 = (const float*)d_in[2];
  const float* b2 = (const float*)d_in[3];
  const float* W0 = (const float*)d_in[4];
  const float* W1 = (const float*)d_in[5];
  const int*   ni = (const int*)d_in[6];
  float* out = (float*)d_out;

  char* ws = (char*)d_ws;
  int*   flags  = (int*)ws;                    // 8 slots x 128 B = 1 KB
  float* aPartG = (float*)(ws + 1024);         // 4 slots x 8 x 128 f32 = 16 KB
  float* part   = (float*)(ws + 1024 + 16384); // nblk x 128 f32

  const int nrows = in_sizes[0];  // 262144
  const size_t hdr = 1024 + 16384;
  int nblk;
  if (ws_size >= hdr + (size_t)(nrows / 256) * 512) {
    nblk = nrows / 256;  // 1024 blocks, 4/CU
    hipLaunchKernelGGL(k1_xw0<256>, dim3(nblk), dim3(256), 0, stream,
                       x, W0, part, flags);
  } else if (ws_size >= hdr + (size_t)(nrows / 512) * 512) {
    nblk = nrows / 512;
    hipLaunchKernelGGL(k1_xw0<512>, dim3(nblk), dim3(256), 0, stream,
                       x, W0, part, flags);
  } else {
    nblk = nrows / 1024;
    hipLaunchKernelGGL(k1_xw0<1024>, dim3(nblk), dim3(256), 0, stream,
                       x, W0, part, flags);
  }
  hipLaunchKernelGGL(k2_iter, dim3(NBLK_B), dim3(256), 0, stream,
                     part, nblk, W1, b1, b2, ni, aPartG, flags, out);
}

// Round 4
// 91.168 us; speedup vs baseline: 1.6006x; 1.6006x over previous
//
#include <hip/hip_runtime.h>
#include <math.h>

#define NBLK_B 8  // phase-B persistent blocks (cols of W1 partitioned 8 x 128)

__device__ __forceinline__ float rho(float s) {
  return fminf(fmaxf(s, 0.0f), 1.0f);
}

// d/ds clip(s,0,1) with JAX maximum/minimum tie-gradient = 0.5
__device__ __forceinline__ float drho(float s) {
  if (s < 0.0f || s > 1.0f) return 0.0f;
  float g = 1.0f;
  if (s == 0.0f) g *= 0.5f;
  if (s == 1.0f) g *= 0.5f;
  return g;
}

// ---------------- Phase A: per-block partials of c0 = rho(x) @ W0 ----------
template <int ROWS>
__global__ __launch_bounds__(256) void k1_xw0(const float* __restrict__ x,
                                              const float* __restrict__ W0,
                                              float* __restrict__ part,
                                              int* __restrict__ flags) {
  __shared__ float xs[ROWS];
  __shared__ float red[8][132];
  const int t = threadIdx.x;
  const int b = blockIdx.x;
  if (b == 0 && t < NBLK_B) flags[t * 32] = 0;  // reset phase-B flags (replay!)
  const int r0 = b * ROWS;
  for (int i = t; i < ROWS; i += 256) xs[i] = rho(x[r0 + i]);
  __syncthreads();
  const int cq = t & 31;   // float4 column group (32 x 4 = 128 cols)
  const int rg = t >> 5;   // row group 0..7
  constexpr int GR = ROWS / 8;
  const float4* __restrict__ W4 = reinterpret_cast<const float4*>(W0);
  float ax = 0.f, ay = 0.f, az = 0.f, aw = 0.f;
  const int base = (r0 + rg * GR) * 32 + cq;
#pragma unroll 8
  for (int i = 0; i < GR; ++i) {
    const float xv = xs[rg * GR + i];
    const float4 w = W4[base + i * 32];
    ax = fmaf(xv, w.x, ax);
    ay = fmaf(xv, w.y, ay);
    az = fmaf(xv, w.z, az);
    aw = fmaf(xv, w.w, aw);
  }
  red[rg][cq * 4 + 0] = ax;
  red[rg][cq * 4 + 1] = ay;
  red[rg][cq * 4 + 2] = az;
  red[rg][cq * 4 + 3] = aw;
  __syncthreads();
  if (t < 128) {
    float s = 0.f;
#pragma unroll
    for (int g = 0; g < 8; ++g) s += red[g][t];
    part[b * 128 + t] = s;
  }
}

// ---------------- Phase A2: tree-reduce part1 (nblk x 128) -> part2 --------
// Block i reduces 32 rows, fully unrolled (16 independent loads in flight).
__global__ __launch_bounds__(256) void k1b_reduce(const float* __restrict__ part1,
                                                  float* __restrict__ part2) {
  __shared__ float acc[2][128];
  const int t = threadIdx.x, i = blockIdx.x;
  const int jk = t & 127, half = t >> 7;
  float s = 0.f;
  const int r0 = i * 32 + half * 16;
#pragma unroll
  for (int r = 0; r < 16; ++r) s += part1[(r0 + r) * 128 + jk];
  acc[half][jk] = s;
  __syncthreads();
  if (half == 0) part2[i * 128 + jk] = acc[0][jk] + acc[1][jk];
}

// ---------------- Phase B: persistent 8-block Adam iterator -----------------
// Per iter: poll(stale flag, hits) -> issue gather loads EARLY -> accB ->
// o-update -> accA -> publish a(t+1)+flag -> h-update consumes gather.
__global__ __launch_bounds__(256) void k2_iter(const float* __restrict__ part2,
                                               const int npart2,
                                               const float* __restrict__ W1,
                                               const float* __restrict__ b1,
                                               const float* __restrict__ b2,
                                               const int* __restrict__ niterp,
                                               float* __restrict__ aPartG,
                                               int* __restrict__ flags,
                                               float* __restrict__ out) {
  __shared__ float w1s[128 * 128];  // 64 KB, elem (j,c) at j*128 + (c ^ (j&31))
  __shared__ float rhs_[128];
  __shared__ float ros_[128];
  __shared__ float c0s[128];
  __shared__ float b1s[128];
  __shared__ float bpart[2][128];
  __shared__ float apl[2][128];

  const int t = threadIdx.x;
  const int p = blockIdx.x;
  const int jk = t & 127;
  const int half = t >> 7;

  // stage W1[:, 128p:128p+128)  (row stride 1024 floats = 256 float4)
  const float4* __restrict__ W14 = reinterpret_cast<const float4*>(W1);
#pragma unroll
  for (int itr = 0; itr < 16; ++itr) {
    const int e4 = itr * 256 + t;
    const int j = e4 >> 5;
    const int c4 = e4 & 31;
    const float4 w = W14[j * 256 + p * 32 + c4];
    const int rb = j * 128;
    const int sw = j & 31;
    const int c = c4 * 4;
    w1s[rb + ((c + 0) ^ sw)] = w.x;
    w1s[rb + ((c + 1) ^ sw)] = w.y;
    w1s[rb + ((c + 2) ^ sw)] = w.z;
    w1s[rb + ((c + 3) ^ sw)] = w.w;
  }
  // c0 from the small part2 (<=32 rows): unrolled, fixed order, replicated
  {
    float s = 0.f;
#pragma unroll 8
    for (int r = half; r < npart2; r += 2) s += part2[r * 128 + jk];
    bpart[half][jk] = s;
  }
  const int niter = *niterp;
  const float b2v = (half == 0) ? b2[p * 128 + jk] : 0.f;
  __syncthreads();
  if (half == 0) {
    c0s[jk] = bpart[0][jk] + bpart[1][jk];
    b1s[jk] = b1[jk];
    rhs_[jk] = 0.f;
    ros_[jk] = 0.f;
    // pre-publish a(1) = W1 @ rho(o_1=0) = 0 into slot 1
    __hip_atomic_store(&aPartG[1 * 1024 + p * 128 + jk], 0.f,
                       __ATOMIC_RELAXED, __HIP_MEMORY_SCOPE_AGENT);
  }
  __syncthreads();
  if (t == 0) {
    __threadfence();
    __hip_atomic_store(&flags[p * 32], 1, __ATOMIC_RELEASE,
                       __HIP_MEMORY_SCOPE_AGENT);
  }

  float hreg = 0.f, mh = 0.f, vh = 0.f;
  float oreg = 0.f, mo = 0.f, vo = 0.f;
  float p1 = 1.f, p2 = 1.f;
  const int x0 = half * 64;

  for (int it = 1; it <= niter; ++it) {
    p1 *= 0.9f;
    p2 *= 0.999f;
    const float bc1 = 1.0f - p1;
    const float bc2 = 1.0f - p2;
    // 0) poll for flag >= it : published by remotes one iteration ago -> hits
    if (t < NBLK_B) {
      while (__hip_atomic_load(&flags[t * 32], __ATOMIC_ACQUIRE,
                               __HIP_MEMORY_SCOPE_AGENT) < it)
        __builtin_amdgcn_s_sleep(1);
    }
    __syncthreads();  // P
    // 1) issue gather loads EARLY; latency hides under accB/o-update/accA.
    //    Safe: slot it&3 can't be overwritten until we publish flag it+2.
    float ga[NBLK_B];
    if (half == 0) {
      const int rslot = it & 3;
#pragma unroll
      for (int q = 0; q < NBLK_B; ++q)
        ga[q] = __hip_atomic_load(&aPartG[rslot * 1024 + q * 128 + jk],
                                  __ATOMIC_RELAXED, __HIP_MEMORY_SCOPE_AGENT);
    }
    // 2) accB = rho(h_t) @ W1[:,own] over own 64 rows (4-way split accum)
    {
      float a0 = 0.f, a1 = 0.f, a2 = 0.f, a3 = 0.f;
#pragma unroll
      for (int u = 0; u < 64; u += 4) {
        const int j0 = x0 + u;
        a0 = fmaf(rhs_[j0 + 0], w1s[(j0 + 0) * 128 + (jk ^ ((j0 + 0) & 31))], a0);
        a1 = fmaf(rhs_[j0 + 1], w1s[(j0 + 1) * 128 + (jk ^ ((j0 + 1) & 31))], a1);
        a2 = fmaf(rhs_[j0 + 2], w1s[(j0 + 2) * 128 + (jk ^ ((j0 + 2) & 31))], a2);
        a3 = fmaf(rhs_[j0 + 3], w1s[(j0 + 3) * 128 + (jk ^ ((j0 + 3) & 31))], a3);
      }
      bpart[half][jk] = (a0 + a1) + (a2 + a3);
    }
    __syncthreads();  // A
    // 3) o-update (purely local) -> o_{t+1}; publish rho(o_{t+1})
    if (half == 0) {
      const float bsum = bpart[0][jk] + bpart[1][jk];
      const float rot = rho(oreg);
      const float go = drho(oreg) * (rot - b2v - bsum);
      mo = 0.9f * mo + 0.1f * go;
      vo = 0.999f * vo + 0.001f * (go * go);
      oreg = oreg - 0.01f * (mo / bc1) / (sqrtf(vo / bc2) + 1e-8f);
      ros_[jk] = rho(oreg);
    }
    __syncthreads();  // B
    // 4) accA(t+1) = W1[own cols] @ rho(o_{t+1}) -> publish 1 iter ahead
    {
      float a0 = 0.f, a1 = 0.f, a2 = 0.f, a3 = 0.f;
#pragma unroll
      for (int u = 0; u < 64; u += 4) {
        const int c0i = x0 + u;
        a0 = fmaf(w1s[jk * 128 + ((c0i + 0) ^ (jk & 31))], ros_[c0i + 0], a0);
        a1 = fmaf(w1s[jk * 128 + ((c0i + 1) ^ (jk & 31))], ros_[c0i + 1], a1);
        a2 = fmaf(w1s[jk * 128 + ((c0i + 2) ^ (jk & 31))], ros_[c0i + 2], a2);
        a3 = fmaf(w1s[jk * 128 + ((c0i + 3) ^ (jk & 31))], ros_[c0i + 3], a3);
      }
      apl[half][jk] = (a0 + a1) + (a2 + a3);
    }
    __syncthreads();  // C
    if (half == 0)
      __hip_atomic_store(&aPartG[((it + 1) & 3) * 1024 + p * 128 + jk],
                         apl[0][jk] + apl[1][jk], __ATOMIC_RELAXED,
                         __HIP_MEMORY_SCOPE_AGENT);
    __syncthreads();  // D
    if (t == 0) {
      __threadfence();
      __hip_atomic_store(&flags[p * 32], it + 1, __ATOMIC_RELEASE,
                         __HIP_MEMORY_SCOPE_AGENT);
    }
    // 5) h-update consumes the early gather (loads long since landed)
    if (half == 0) {
      const float a = ((ga[0] + ga[1]) + (ga[2] + ga[3])) +
                      ((ga[4] + ga[5]) + (ga[6] + ga[7]));
      const float gh = drho(hreg) * (rhs_[jk] - b1s[jk] - c0s[jk] - a);
      mh = 0.9f * mh + 0.1f * gh;
      vh = 0.999f * vh + 0.001f * (gh * gh);
      hreg = hreg - 0.01f * (mh / bc1) / (sqrtf(vh / bc2) + 1e-8f);
      rhs_[jk] = rho(hreg);
    }
    __syncthreads();  // F
  }
  if (half == 0) out[p * 128 + jk] = oreg;
}

extern "C" void kernel_launch(void* const* d_in, const int* in_sizes, int n_in,
                              void* d_out, int out_size, void* d_ws,
                              size_t ws_size, hipStream_t stream) {
  const float* x  = (const float*)d_in[0];
  // d_in[1] = b0: constant in E w.r.t. (h,o) -> never needed
  const float* b1 = (const float*)d_in[2];
  const float* b2 = (const float*)d_in[3];
  const float* W0 = (const float*)d_in[4];
  const float* W1 = (const float*)d_in[5];
  const int*   ni = (const int*)d_in[6];
  float* out = (float*)d_out;

  char* ws = (char*)d_ws;
  int*   flags  = (int*)ws;                     // 8 slots x 128 B = 1 KB
  float* aPartG = (float*)(ws + 1024);          // 4 slots x 8 x 128 f32 = 16 KB
  float* part2  = (float*)(ws + 1024 + 16384);  // <=32 x 128 f32 = 16 KB
  float* part1  = (float*)(ws + 1024 + 16384 + 16384);

  const int nrows = in_sizes[0];  // 262144
  const size_t hdr = 1024 + 16384 + 16384;
  int nblk1;
  if (ws_size >= hdr + (size_t)(nrows / 256) * 512) {
    nblk1 = nrows / 256;  // 1024 blocks, 4/CU
    hipLaunchKernelGGL(k1_xw0<256>, dim3(nblk1), dim3(256), 0, stream,
                       x, W0, part1, flags);
  } else if (ws_size >= hdr + (size_t)(nrows / 512) * 512) {
    nblk1 = nrows / 512;
    hipLaunchKernelGGL(k1_xw0<512>, dim3(nblk1), dim3(256), 0, stream,
                       x, W0, part1, flags);
  } else {
    nblk1 = nrows / 1024;
    hipLaunchKernelGGL(k1_xw0<1024>, dim3(nblk1), dim3(256), 0, stream,
                       x, W0, part1, flags);
  }
  const int nblk2 = nblk1 / 32;  // 32 rows per k1b block
  hipLaunchKernelGGL(k1b_reduce, dim3(nblk2), dim3(256), 0, stream,
                     part1, part2);
  hipLaunchKernelGGL(k2_iter, dim3(NBLK_B), dim3(256), 0, stream,
                     part2, nblk2, W1, b1, b2, ni, aPartG, flags, out);
}